// Round 20
// baseline (178.560 us; speedup 1.0000x reference)
//
#include <hip/hip_runtime.h>
#include <hip/hip_fp16.h>
#include <hip/hip_cooperative_groups.h>

namespace cg = cooperative_groups;

#define NATOMS 2048
#define CCH    64
#define NE     4

#define NP    136
#define K3DIM 2176
#define M2B   2176
#define M1B   2312
#define KTOT  2328
#define KPAD  2336
#define NSTEP 73
#define MAXBS 12
#define GRIDN 768

typedef _Float16 f16x8 __attribute__((ext_vector_type(8)));
typedef float f32x4 __attribute__((ext_vector_type(4)));

__host__ __device__ constexpr int pair_i(int p){ int i=0, rem=p; while (rem >= 16-i){ rem -= 16-i; ++i; } return i; }
__host__ __device__ constexpr int pair_j(int p){ int i=0, rem=p; while (rem >= 16-i){ rem -= 16-i; ++i; } return i+rem; }

struct PTab { unsigned v[68]; };
__host__ __device__ constexpr PTab make_ptab(){
  PTab t{};
  for (int s = 0; s < 68; ++s){
    int p0 = 2*s, p1 = 2*s + 1;
    t.v[s] = (unsigned)(pair_i(p0) | (pair_j(p0)<<5) | (pair_i(p1)<<10) | (pair_j(p1)<<15));
  }
  return t;
}
__device__ __constant__ PTab ptab = make_ptab();

__device__ __forceinline__ __half2 uh(unsigned u){ union{unsigned x;__half2 h;}c; c.x=u; return c.h; }

__device__ __forceinline__ void slot_decode(const int* counts, int g,
                                            int& e, int& b0, int& cnt, int& ns){
  int c0 = counts[0], c1 = counts[1], c2 = counts[2], c3 = counts[3];
  int n0 = (c0+255)>>8, n1 = (c1+255)>>8, n2 = (c2+255)>>8, n3 = (c3+255)>>8;
  ns = n0 + n1 + n2 + n3;
  if (g < n0){ e = 0; b0 = g*256; cnt = c0; }
  else if (g < n0+n1){ e = 1; b0 = (g-n0)*256; cnt = c1; }
  else if (g < n0+n1+n2){ e = 2; b0 = (g-n0-n1)*256; cnt = c2; }
  else { e = 3; b0 = (g-n0-n1-n2)*256; cnt = c3; }
}

__device__ __forceinline__ void pack2(unsigned a, unsigned b, unsigned& lo, unsigned& hi){
  lo = (a & 0xFFFFu) | (b << 16);
  hi = (a >> 16) | (b & 0xFFFF0000u);
}

// ---------------- shared phase-1 bodies ----------------
__device__ __forceinline__ void do_bin(const int* __restrict__ types, int* __restrict__ counts,
                                       int* __restrict__ bins, char* smem, int tid){
  int (*hist)[4] = (int(*)[4])smem;
  int ty[8];
  int h0=0,h1=0,h2=0,h3=0;
#pragma unroll
  for (int q = 0; q < 8; ++q){
    int t = types[tid*8 + q] & 3;
    ty[q] = t;
    h0 += (t==0); h1 += (t==1); h2 += (t==2); h3 += (t==3);
  }
  hist[tid][0]=h0; hist[tid][1]=h1; hist[tid][2]=h2; hist[tid][3]=h3;
  __syncthreads();
  if (tid == 0){
    int r0=0,r1=0,r2=0,r3=0;
    for (int t = 0; t < 256; ++t){
      int a=hist[t][0], b=hist[t][1], c2=hist[t][2], d=hist[t][3];
      hist[t][0]=r0; hist[t][1]=r1; hist[t][2]=r2; hist[t][3]=r3;
      r0+=a; r1+=b; r2+=c2; r3+=d;
    }
    counts[0]=r0; counts[1]=r1; counts[2]=r2; counts[3]=r3;
  }
  __syncthreads();
  int p0=hist[tid][0], p1=hist[tid][1], p2=hist[tid][2], p3=hist[tid][3];
#pragma unroll
  for (int q = 0; q < 8; ++q){
    int n = tid*8 + q, t = ty[q];
    int pos;
    if      (t==0) pos = p0++;
    else if (t==1) pos = p1++;
    else if (t==2) pos = p2++;
    else           pos = p3++;
    bins[t*NATOMS + pos] = n;
  }
}

__device__ __forceinline__ void do_fold(int fid,
    const float* __restrict__ U3, const float* __restrict__ U2, const float* __restrict__ U1,
    const float* __restrict__ W3, const float* __restrict__ W2, const float* __restrict__ W1,
    unsigned int* __restrict__ Bbuf, char* smem, int tid){
  int se = fid >> 1, half = fid & 1;
  int s = se % NSTEP, e = se / NSTEP;
  int ccBase = half * 32;
  int l = tid >> 2, r = tid & 3, g = l >> 4, L = l & 15;
  int m0 = 32*s + 8*g + 2*r;
  float (*WL)[CCH] = (float(*)[CCH])smem;

  for (int t = tid; t < 33*CCH; t += 256){
    int row = t >> 6, cc = t & 63;
    float v = 0.f;
    if (row < 23)      v = W3[((size_t)e*23 + row)*CCH + cc];
    else if (row < 28) v = W2[((size_t)e*5 + (row-23))*CCH + cc];
    else if (row < 30) v = W1[((size_t)e*2 + (row-28))*CCH + cc];
    WL[row][cc] = v;
  }
  __syncthreads();

  float u0[24], u1[24];
#pragma unroll
  for (int w = 0; w < 24; ++w){ u0[w] = 0.f; u1[w] = 0.f; }

  if (s < 68){
    int p = m0 >> 4, k = m0 & 15;
    int i = 0, rem = p; while (rem >= 16 - i){ rem -= 16 - i; ++i; }
    int j = i + rem;
    const float* rA = &U3[((((size_t)L*16 + i)*16 + j)*16 + k)*23];
    if (i < j){
      const float* rB = &U3[((((size_t)L*16 + j)*16 + i)*16 + k)*23];
#pragma unroll
      for (int w = 0; w < 23; ++w){
        u0[w] = rA[w]      + rB[w];
        u1[w] = rA[23 + w] + rB[23 + w];
      }
    } else {
#pragma unroll
      for (int w = 0; w < 23; ++w){
        u0[w] = rA[w];
        u1[w] = rA[23 + w];
      }
    }
  } else {
    if (m0 < M1B){
      int p2a = m0 - M2B;
      int i = 0, rem = p2a; while (rem >= 16 - i){ rem -= 16 - i; ++i; }
      int j = i + rem;
#pragma unroll
      for (int w = 0; w < 5; ++w){
        float vv = U2[(((size_t)L*16 + i)*16 + j)*5 + w];
        if (i < j) vv += U2[(((size_t)L*16 + j)*16 + i)*5 + w];
        u0[w] = vv;
      }
      int p2b = p2a + 1;
      i = 0; rem = p2b; while (rem >= 16 - i){ rem -= 16 - i; ++i; }
      j = i + rem;
#pragma unroll
      for (int w = 0; w < 5; ++w){
        float vv = U2[(((size_t)L*16 + i)*16 + j)*5 + w];
        if (i < j) vv += U2[(((size_t)L*16 + j)*16 + i)*5 + w];
        u1[w] = vv;
      }
    } else if (m0 < KTOT){
      int i = m0 - M1B;
      u0[0] = U1[((size_t)L*16 + i)*2 + 0];
      u0[1] = U1[((size_t)L*16 + i)*2 + 1];
      u1[0] = U1[((size_t)L*16 + i + 1)*2 + 0];
      u1[1] = U1[((size_t)L*16 + i + 1)*2 + 1];
    }
  }

  const size_t ostride = (size_t)NSTEP*64*4;
  size_t obase = (((size_t)(e*CCH)*NSTEP + s)*64 + l)*4 + r;

  if (s < 68){
    for (int cc0 = ccBase; cc0 < ccBase + 32; cc0 += 4){
      float a0[4] = {0,0,0,0}, a1[4] = {0,0,0,0};
#pragma unroll
      for (int w = 0; w < 23; ++w){
#pragma unroll
        for (int q = 0; q < 4; ++q){
          float wv = WL[w][cc0+q];
          a0[q] += u0[w]*wv; a1[q] += u1[w]*wv;
        }
      }
#pragma unroll
      for (int q = 0; q < 4; ++q){
        union { __half2 h; unsigned int u; } hu;
        hu.h = __halves2half2(__float2half(a0[q]), __float2half(a1[q]));
        Bbuf[obase + (size_t)(cc0+q)*ostride] = hu.u;
      }
    }
  } else {
    int wbase = (m0 < M1B) ? 23 : 28;
    for (int cc0 = ccBase; cc0 < ccBase + 32; cc0 += 4){
      float a0[4] = {0,0,0,0}, a1[4] = {0,0,0,0};
#pragma unroll
      for (int w = 0; w < 5; ++w){
#pragma unroll
        for (int q = 0; q < 4; ++q){
          float wv = WL[wbase + w][cc0+q];
          a0[q] += u0[w]*wv; a1[q] += u1[w]*wv;
        }
      }
#pragma unroll
      for (int q = 0; q < 4; ++q){
        union { __half2 h; unsigned int u; } hu;
        hu.h = __halves2half2(__float2half(a0[q]), __float2half(a1[q]));
        Bbuf[obase + (size_t)(cc0+q)*ostride] = hu.u;
      }
    }
  }
}

__device__ __forceinline__ void do_xpose(int xb, const float* __restrict__ x,
                                         unsigned* __restrict__ xTu, char* smem, int tid){
  int n0 = xb * 16;
  __half (*ls)[1040] = (__half(*)[1040])smem;
  int a_loc = tid >> 4, i = tid & 15;
  int n = n0 + a_loc;
  {
    const float4* src = (const float4*)(x + (size_t)n*1024 + (size_t)i*64);
#pragma unroll
    for (int q = 0; q < 16; ++q){
      float4 v = src[q];
      int c = q*4;
      ls[a_loc][(c+0)*16 + i] = __float2half(v.x);
      ls[a_loc][(c+1)*16 + i] = __float2half(v.y);
      ls[a_loc][(c+2)*16 + i] = __float2half(v.z);
      ls[a_loc][(c+3)*16 + i] = __float2half(v.w);
    }
  }
  __syncthreads();
  int wid = tid >> 6, lane = tid & 63;
  for (int cp = 0; cp < 16; ++cp){
    int c = cp*4 + wid;
#pragma unroll
    for (int h = 0; h < 2; ++h){
      int a = h*8 + (lane >> 3), i2 = lane & 7;
      __half lo = ls[a][c*16 + 2*i2];
      __half hi = ls[a][c*16 + 2*i2 + 1];
      union { __half2 h2; unsigned u; } pk;
      pk.h2 = __halves2half2(lo, hi);
      xTu[((size_t)c*NATOMS + n0 + a)*8 + i2] = pk.u;
    }
  }
}

// ---------------- main body (phase 2) ----------------
__device__ __forceinline__ void do_main(int blk, int tid,
    const unsigned* __restrict__ xTu, const int* __restrict__ counts,
    const int* __restrict__ bins, const uint4* __restrict__ Bb,
    float* __restrict__ out, char* smem){
  int v = (blk & 7) * 96 + (blk >> 3);
  int c = v / MAXBS;
  int g = v % MAXBS;
  int e, b0, cnt, ns;
  slot_decode(counts, g, e, b0, cnt, ns);
  if (g >= ns) return;

  int wid = tid >> 6, lane = tid & 63;
  uint2 (*xe)[19] = (uint2(*)[19])smem;
  unsigned* ltab  = (unsigned*)(smem + 38912);

  bool hi_half = (lane & 16) != 0;
  bool gsel    = (lane & 32) != 0;

  const uint4* xbase = (const uint4*)xTu;
  uint4 tv0[4], tv1[4];
  __half2 xsel[4][4];
#pragma unroll
  for (int T = 0; T < 4; ++T){
    int row = b0 + wid*64 + T*16 + (lane & 15);
    int n = (row < cnt) ? bins[e*NATOMS + row] : -1;
    if (n >= 0){
      const uint4* xr = xbase + ((size_t)c*NATOMS + n)*2;
      tv0[T] = xr[0];
      tv1[T] = xr[1];
    } else {
      tv0[T] = make_uint4(0,0,0,0);
      tv1[T] = make_uint4(0,0,0,0);
    }
    xsel[T][0] = uh(hi_half ? tv1[T].x : tv0[T].x);
    xsel[T][1] = uh(hi_half ? tv1[T].y : tv0[T].y);
    xsel[T][2] = uh(hi_half ? tv1[T].z : tv0[T].z);
    xsel[T][3] = uh(hi_half ? tv1[T].w : tv0[T].w);
  }
  __syncthreads();
  {
    unsigned alo, ahi, blo, bhi;
    pack2(tv0[0].x, tv0[1].x, alo, ahi); pack2(tv0[2].x, tv0[3].x, blo, bhi);
    xe[tid][0] = make_uint2(alo, blo); xe[tid][1] = make_uint2(ahi, bhi);
    pack2(tv0[0].y, tv0[1].y, alo, ahi); pack2(tv0[2].y, tv0[3].y, blo, bhi);
    xe[tid][2] = make_uint2(alo, blo); xe[tid][3] = make_uint2(ahi, bhi);
    pack2(tv0[0].z, tv0[1].z, alo, ahi); pack2(tv0[2].z, tv0[3].z, blo, bhi);
    xe[tid][4] = make_uint2(alo, blo); xe[tid][5] = make_uint2(ahi, bhi);
    pack2(tv0[0].w, tv0[1].w, alo, ahi); pack2(tv0[2].w, tv0[3].w, blo, bhi);
    xe[tid][6] = make_uint2(alo, blo); xe[tid][7] = make_uint2(ahi, bhi);
    pack2(tv1[0].x, tv1[1].x, alo, ahi); pack2(tv1[2].x, tv1[3].x, blo, bhi);
    xe[tid][8] = make_uint2(alo, blo); xe[tid][9] = make_uint2(ahi, bhi);
    pack2(tv1[0].y, tv1[1].y, alo, ahi); pack2(tv1[2].y, tv1[3].y, blo, bhi);
    xe[tid][10] = make_uint2(alo, blo); xe[tid][11] = make_uint2(ahi, bhi);
    pack2(tv1[0].z, tv1[1].z, alo, ahi); pack2(tv1[2].z, tv1[3].z, blo, bhi);
    xe[tid][12] = make_uint2(alo, blo); xe[tid][13] = make_uint2(ahi, bhi);
    pack2(tv1[0].w, tv1[1].w, alo, ahi); pack2(tv1[2].w, tv1[3].w, blo, bhi);
    xe[tid][14] = make_uint2(alo, blo); xe[tid][15] = make_uint2(ahi, bhi);
    xe[tid][16] = make_uint2(0x3C003C00u, 0x3C003C00u);
    xe[tid][17] = make_uint2(0u, 0u);
  }
  if (tid < 160){
    unsigned ij;
    if (tid < NP)        ij = (unsigned)(pair_i(tid) | (pair_j(tid) << 8));
    else if (tid < 152)  ij = (unsigned)((tid - NP) | (16 << 8));
    else                 ij = (unsigned)(17 | (17 << 8));
    ltab[tid] = ij;
  }
  __syncthreads();

  const uint4* Bpan = Bb + (size_t)(e*CCH + c)*NSTEP*64 + lane;

  f32x4 acc0 = {0,0,0,0}, acc1 = {0,0,0,0}, acc2 = {0,0,0,0}, acc3 = {0,0,0,0};
  uint4 pb0 = Bpan[0*64], pb1 = Bpan[1*64], pb2 = Bpan[2*64], pb3 = Bpan[3*64];

  unsigned pk0 = ptab.v[0];
  int is = gsel ? ((pk0>>10)&31) : (pk0&31);
  int js = gsel ? ((pk0>>15)&31) : ((pk0>>5)&31);
  uint2 pi = xe[tid][is], pj = xe[tid][js];

#pragma unroll 4
  for (int s = 0; s < 68; ++s){
    uint2 npi = pi, npj = pj;
    if (s < 67){
      unsigned pk = ptab.v[s+1];
      int is2 = gsel ? ((pk>>10)&31) : (pk&31);
      int js2 = gsel ? ((pk>>15)&31) : ((pk>>5)&31);
      npi = xe[tid][is2]; npj = xe[tid][js2];
    }
    uint4 cur = pb0; pb0 = pb1; pb1 = pb2; pb2 = pb3;
    int ld = (s + 4 <= 72) ? (s + 4) : 72;
    pb3 = Bpan[(size_t)ld*64];

    __half2 p01 = __hmul2(uh(pi.x), uh(pj.x));
    __half2 p23 = __hmul2(uh(pi.y), uh(pj.y));

    union { uint4 u; f16x8 h; } bc; bc.u = cur;
    __half2 pv0 = __half2half2(__low2half(p01));
    __half2 pv1 = __half2half2(__high2half(p01));
    __half2 pv2 = __half2half2(__low2half(p23));
    __half2 pv3 = __half2half2(__high2half(p23));
    union { __half2 h[4]; f16x8 v; } u0, u1, u2, u3;
#pragma unroll
    for (int q = 0; q < 4; ++q){
      u0.h[q] = __hmul2(pv0, xsel[0][q]);
      u1.h[q] = __hmul2(pv1, xsel[1][q]);
      u2.h[q] = __hmul2(pv2, xsel[2][q]);
      u3.h[q] = __hmul2(pv3, xsel[3][q]);
    }
    acc0 = __builtin_amdgcn_mfma_f32_16x16x32_f16(u0.v, bc.h, acc0, 0,0,0);
    acc1 = __builtin_amdgcn_mfma_f32_16x16x32_f16(u1.v, bc.h, acc1, 0,0,0);
    acc2 = __builtin_amdgcn_mfma_f32_16x16x32_f16(u2.v, bc.h, acc2, 0,0,0);
    acc3 = __builtin_amdgcn_mfma_f32_16x16x32_f16(u3.v, bc.h, acc3, 0,0,0);
    pi = npi; pj = npj;
  }

  int g2 = (lane >> 4) & 3;
#pragma unroll
  for (int s = 68; s < 73; ++s){
    uint4 cur = pb0; pb0 = pb1; pb1 = pb2; pb2 = pb3;
    pb3 = Bpan[(size_t)72*64];
    int mb = 32*s + 8*g2 - M2B;
    union { uint4 u; f16x8 h; } bc; bc.u = cur;
    union { __half2 h[4]; f16x8 v; } u0, u1, u2, u3;
#pragma unroll
    for (int q = 0; q < 4; ++q){
      unsigned ta = ltab[mb + 2*q], tb = ltab[mb + 2*q + 1];
      uint2 A = xe[tid][ta & 255], B = xe[tid][ta >> 8];
      uint2 C = xe[tid][tb & 255], D = xe[tid][tb >> 8];
      __half2 pa01 = __hmul2(uh(A.x), uh(B.x));
      __half2 pb01 = __hmul2(uh(C.x), uh(D.x));
      __half2 pa23 = __hmul2(uh(A.y), uh(B.y));
      __half2 pb23 = __hmul2(uh(C.y), uh(D.y));
      u0.h[q] = __halves2half2(__low2half(pa01),  __low2half(pb01));
      u1.h[q] = __halves2half2(__high2half(pa01), __high2half(pb01));
      u2.h[q] = __halves2half2(__low2half(pa23),  __low2half(pb23));
      u3.h[q] = __halves2half2(__high2half(pa23), __high2half(pb23));
    }
    acc0 = __builtin_amdgcn_mfma_f32_16x16x32_f16(u0.v, bc.h, acc0, 0,0,0);
    acc1 = __builtin_amdgcn_mfma_f32_16x16x32_f16(u1.v, bc.h, acc1, 0,0,0);
    acc2 = __builtin_amdgcn_mfma_f32_16x16x32_f16(u2.v, bc.h, acc2, 0,0,0);
    acc3 = __builtin_amdgcn_mfma_f32_16x16x32_f16(u3.v, bc.h, acc3, 0,0,0);
  }

  int gp = lane >> 4, L = lane & 15;
#pragma unroll
  for (int T = 0; T < 4; ++T){
    f32x4 a = (T==0) ? acc0 : (T==1) ? acc1 : (T==2) ? acc2 : acc3;
    int rb = b0 + wid*64 + T*16;
#pragma unroll
    for (int r = 0; r < 4; ++r){
      int row = rb + 4*gp + r;
      if (row < cnt){
        int n = bins[e*NATOMS + row];
        out[((size_t)n*16 + L)*CCH + c] = a[r];
      }
    }
  }
}

// ================= cooperative fused =================
__global__ __launch_bounds__(256, 4) void fused_kernel(
    const int* __restrict__ types, int* __restrict__ counts, int* __restrict__ bins,
    const float* __restrict__ U3, const float* __restrict__ U2, const float* __restrict__ U1,
    const float* __restrict__ W3, const float* __restrict__ W2, const float* __restrict__ W1,
    unsigned int* __restrict__ Bbuf, const float* __restrict__ x, unsigned* __restrict__ xTu,
    float* __restrict__ out){
  __shared__ char smem[39552];
  int blk = blockIdx.x;
  int tid = threadIdx.x;

  if (blk == 0)                       do_bin(types, counts, bins, smem, tid);
  else if (blk <= 2*NSTEP*NE)         do_fold(blk - 1, U3, U2, U1, W3, W2, W1, Bbuf, smem, tid);
  else if (blk <= 2*NSTEP*NE + 128)   do_xpose(blk - 1 - 2*NSTEP*NE, x, xTu, smem, tid);

  cg::this_grid().sync();

  do_main(blk, tid, xTu, counts, bins, (const uint4*)Bbuf, out, smem);
}

// ================= fallback pair =================
__global__ __launch_bounds__(256) void prep_all(
    const int* __restrict__ types, int* __restrict__ counts, int* __restrict__ bins,
    const float* __restrict__ U3, const float* __restrict__ U2, const float* __restrict__ U1,
    const float* __restrict__ W3, const float* __restrict__ W2, const float* __restrict__ W1,
    unsigned int* __restrict__ Bbuf, const float* __restrict__ x, unsigned* __restrict__ xTu){
  __shared__ char smem[39552];
  int blk = blockIdx.x;
  int tid = threadIdx.x;
  if (blk == 0)                       do_bin(types, counts, bins, smem, tid);
  else if (blk <= 2*NSTEP*NE)         do_fold(blk - 1, U3, U2, U1, W3, W2, W1, Bbuf, smem, tid);
  else                                do_xpose(blk - 1 - 2*NSTEP*NE, x, xTu, smem, tid);
}

__global__ __launch_bounds__(256, 4) void main9_kernel(
    const unsigned* __restrict__ xTu, const int* __restrict__ counts,
    const int* __restrict__ bins, const uint4* __restrict__ Bbuf,
    float* __restrict__ out){
  __shared__ char smem[39552];
  do_main(blockIdx.x, threadIdx.x, xTu, counts, bins, Bbuf, out, smem);
}

extern "C" void kernel_launch(void* const* d_in, const int* in_sizes, int n_in,
                              void* d_out, int out_size, void* d_ws, size_t ws_size,
                              hipStream_t stream){
  const float* x   = (const float*)d_in[0];
  const int* types = (const int*)d_in[1];
  const float* U3  = (const float*)d_in[2];
  const float* U2  = (const float*)d_in[3];
  const float* U1  = (const float*)d_in[4];
  const float* W3  = (const float*)d_in[5];
  const float* W2  = (const float*)d_in[6];
  const float* W1  = (const float*)d_in[7];
  float* out = (float*)d_out;

  char* ws = (char*)d_ws;
  int* counts  = (int*)ws;
  int* bins    = (int*)(ws + 1024);

  const size_t bbOff   = 33792;
  const size_t bbBytes = (size_t)NE * 64 * NSTEP * 64 * 16;   // 19,136,512
  const size_t xtOff   = bbOff + bbBytes;                     // 19,170,304

  unsigned int* Bbuf = (unsigned int*)(ws + bbOff);
  unsigned* xTu = (unsigned*)(ws + xtOff);

  void* args[] = { (void*)&types, (void*)&counts, (void*)&bins,
                   (void*)&U3, (void*)&U2, (void*)&U1,
                   (void*)&W3, (void*)&W2, (void*)&W1,
                   (void*)&Bbuf, (void*)&x, (void*)&xTu, (void*)&out };
  hipError_t err = hipLaunchCooperativeKernel((void*)fused_kernel, dim3(GRIDN), dim3(256),
                                              args, 0, stream);
  if (err != hipSuccess){
    (void)hipGetLastError();   // clear sticky error
    prep_all<<<1 + 2*NSTEP*NE + 128, 256, 0, stream>>>(types, counts, bins,
                                                       U3, U2, U1, W3, W2, W1,
                                                       Bbuf, x, xTu);
    main9_kernel<<<GRIDN, 256, 0, stream>>>(xTu, counts, bins, (const uint4*)Bbuf, out);
  }
}

// Round 21
// 60.442 us; speedup vs baseline: 2.9543x; 2.9543x over previous
//
#include <hip/hip_runtime.h>
#include <hip/hip_fp16.h>

#define NATOMS 2048
#define CCH    64
#define NE     4

#define NP    136
#define K3DIM 2176
#define M2B   2176
#define M1B   2312
#define KTOT  2328
#define KPAD  2336
#define NSTEP 73
#define MAXBS 12
#define GRIDN 768

typedef _Float16 f16x8 __attribute__((ext_vector_type(8)));
typedef float f32x4 __attribute__((ext_vector_type(4)));

__host__ __device__ constexpr int pair_i(int p){ int i=0, rem=p; while (rem >= 16-i){ rem -= 16-i; ++i; } return i; }
__host__ __device__ constexpr int pair_j(int p){ int i=0, rem=p; while (rem >= 16-i){ rem -= 16-i; ++i; } return i+rem; }

struct PTab { unsigned v[68]; };
__host__ __device__ constexpr PTab make_ptab(){
  PTab t{};
  for (int s = 0; s < 68; ++s){
    int p0 = 2*s, p1 = 2*s + 1;
    t.v[s] = (unsigned)(pair_i(p0) | (pair_j(p0)<<5) | (pair_i(p1)<<10) | (pair_j(p1)<<15));
  }
  return t;
}
__device__ __constant__ PTab ptab = make_ptab();

__device__ __forceinline__ __half2 uh(unsigned u){ union{unsigned x;__half2 h;}c; c.x=u; return c.h; }

__device__ __forceinline__ void slot_decode(const int* counts, int g,
                                            int& e, int& b0, int& cnt, int& ns){
  int c0 = counts[0], c1 = counts[1], c2 = counts[2], c3 = counts[3];
  int n0 = (c0+255)>>8, n1 = (c1+255)>>8, n2 = (c2+255)>>8, n3 = (c3+255)>>8;
  ns = n0 + n1 + n2 + n3;
  if (g < n0){ e = 0; b0 = g*256; cnt = c0; }
  else if (g < n0+n1){ e = 1; b0 = (g-n0)*256; cnt = c1; }
  else if (g < n0+n1+n2){ e = 2; b0 = (g-n0-n1)*256; cnt = c2; }
  else { e = 3; b0 = (g-n0-n1-n2)*256; cnt = c3; }
}

__device__ __forceinline__ void pack2(unsigned a, unsigned b, unsigned& lo, unsigned& hi){
  lo = (a & 0xFFFFu) | (b << 16);
  hi = (a >> 16) | (b & 0xFFFF0000u);
}

// ================= K1: bin (block 0) + fold 2-channel-halves (1..584) + xpose (585..712) =================
__global__ __launch_bounds__(256) void prep_all(
    const int* __restrict__ types, int* __restrict__ counts, int* __restrict__ bins,
    const float* __restrict__ U3, const float* __restrict__ U2, const float* __restrict__ U1,
    const float* __restrict__ W3, const float* __restrict__ W2, const float* __restrict__ W1,
    unsigned int* __restrict__ Bbuf, const float* __restrict__ x, unsigned* __restrict__ xTu){
  __shared__ char smem[33280];
  int blk = blockIdx.x;
  int tid = threadIdx.x;

  if (blk == 0){
    int (*hist)[4] = (int(*)[4])smem;
    int ty[8];
    int h0=0,h1=0,h2=0,h3=0;
#pragma unroll
    for (int q = 0; q < 8; ++q){
      int t = types[tid*8 + q] & 3;
      ty[q] = t;
      h0 += (t==0); h1 += (t==1); h2 += (t==2); h3 += (t==3);
    }
    hist[tid][0]=h0; hist[tid][1]=h1; hist[tid][2]=h2; hist[tid][3]=h3;
    __syncthreads();
    if (tid == 0){
      int r0=0,r1=0,r2=0,r3=0;
      for (int t = 0; t < 256; ++t){
        int a=hist[t][0], b=hist[t][1], c2=hist[t][2], d=hist[t][3];
        hist[t][0]=r0; hist[t][1]=r1; hist[t][2]=r2; hist[t][3]=r3;
        r0+=a; r1+=b; r2+=c2; r3+=d;
      }
      counts[0]=r0; counts[1]=r1; counts[2]=r2; counts[3]=r3;
    }
    __syncthreads();
    int p0=hist[tid][0], p1=hist[tid][1], p2=hist[tid][2], p3=hist[tid][3];
#pragma unroll
    for (int q = 0; q < 8; ++q){
      int n = tid*8 + q, t = ty[q];
      int pos;
      if      (t==0) pos = p0++;
      else if (t==1) pos = p1++;
      else if (t==2) pos = p2++;
      else           pos = p3++;
      bins[t*NATOMS + pos] = n;
    }
    return;
  }

  if (blk <= 2*NSTEP*NE){
    // ---- fold with inline usym; 2 channel-halves per (s,e) ----
    int fid = blk - 1;
    int se = fid >> 1, half = fid & 1;
    int s = se % NSTEP, e = se / NSTEP;
    int ccBase = half * 32;
    int l = tid >> 2, r = tid & 3, g = l >> 4, L = l & 15;
    int m0 = 32*s + 8*g + 2*r;
    float (*WL)[CCH] = (float(*)[CCH])smem;

    for (int t = tid; t < 33*CCH; t += 256){
      int row = t >> 6, cc = t & 63;
      float v = 0.f;
      if (row < 23)      v = W3[((size_t)e*23 + row)*CCH + cc];
      else if (row < 28) v = W2[((size_t)e*5 + (row-23))*CCH + cc];
      else if (row < 30) v = W1[((size_t)e*2 + (row-28))*CCH + cc];
      WL[row][cc] = v;
    }
    __syncthreads();

    float u0[24], u1[24];
#pragma unroll
    for (int w = 0; w < 24; ++w){ u0[w] = 0.f; u1[w] = 0.f; }

    if (s < 68){
      int p = m0 >> 4, k = m0 & 15;
      int i = 0, rem = p; while (rem >= 16 - i){ rem -= 16 - i; ++i; }
      int j = i + rem;
      const float* rA = &U3[((((size_t)L*16 + i)*16 + j)*16 + k)*23];
      if (i < j){
        const float* rB = &U3[((((size_t)L*16 + j)*16 + i)*16 + k)*23];
#pragma unroll
        for (int w = 0; w < 23; ++w){
          u0[w] = rA[w]      + rB[w];
          u1[w] = rA[23 + w] + rB[23 + w];
        }
      } else {
#pragma unroll
        for (int w = 0; w < 23; ++w){
          u0[w] = rA[w];
          u1[w] = rA[23 + w];
        }
      }
    } else {
      if (m0 < M1B){
        int p2a = m0 - M2B;
        int i = 0, rem = p2a; while (rem >= 16 - i){ rem -= 16 - i; ++i; }
        int j = i + rem;
#pragma unroll
        for (int w = 0; w < 5; ++w){
          float vv = U2[(((size_t)L*16 + i)*16 + j)*5 + w];
          if (i < j) vv += U2[(((size_t)L*16 + j)*16 + i)*5 + w];
          u0[w] = vv;
        }
        int p2b = p2a + 1;
        i = 0; rem = p2b; while (rem >= 16 - i){ rem -= 16 - i; ++i; }
        j = i + rem;
#pragma unroll
        for (int w = 0; w < 5; ++w){
          float vv = U2[(((size_t)L*16 + i)*16 + j)*5 + w];
          if (i < j) vv += U2[(((size_t)L*16 + j)*16 + i)*5 + w];
          u1[w] = vv;
        }
      } else if (m0 < KTOT){
        int i = m0 - M1B;
        u0[0] = U1[((size_t)L*16 + i)*2 + 0];
        u0[1] = U1[((size_t)L*16 + i)*2 + 1];
        u1[0] = U1[((size_t)L*16 + i + 1)*2 + 0];
        u1[1] = U1[((size_t)L*16 + i + 1)*2 + 1];
      }
    }

    const size_t ostride = (size_t)NSTEP*64*4;
    size_t obase = (((size_t)(e*CCH)*NSTEP + s)*64 + l)*4 + r;

    if (s < 68){
      for (int cc0 = ccBase; cc0 < ccBase + 32; cc0 += 4){
        float a0[4] = {0,0,0,0}, a1[4] = {0,0,0,0};
#pragma unroll
        for (int w = 0; w < 23; ++w){
#pragma unroll
          for (int q = 0; q < 4; ++q){
            float wv = WL[w][cc0+q];
            a0[q] += u0[w]*wv; a1[q] += u1[w]*wv;
          }
        }
#pragma unroll
        for (int q = 0; q < 4; ++q){
          union { __half2 h; unsigned int u; } hu;
          hu.h = __halves2half2(__float2half(a0[q]), __float2half(a1[q]));
          Bbuf[obase + (size_t)(cc0+q)*ostride] = hu.u;
        }
      }
    } else {
      int wbase = (m0 < M1B) ? 23 : 28;
      for (int cc0 = ccBase; cc0 < ccBase + 32; cc0 += 4){
        float a0[4] = {0,0,0,0}, a1[4] = {0,0,0,0};
#pragma unroll
        for (int w = 0; w < 5; ++w){
#pragma unroll
          for (int q = 0; q < 4; ++q){
            float wv = WL[wbase + w][cc0+q];
            a0[q] += u0[w]*wv; a1[q] += u1[w]*wv;
          }
        }
#pragma unroll
        for (int q = 0; q < 4; ++q){
          union { __half2 h; unsigned int u; } hu;
          hu.h = __halves2half2(__float2half(a0[q]), __float2half(a1[q]));
          Bbuf[obase + (size_t)(cc0+q)*ostride] = hu.u;
        }
      }
    }
    return;
  }

  // ---- xpose: plain n-order; xT[c][n] = 16 f16 ----
  int xb = blk - 1 - 2*NSTEP*NE;       // 0..127
  int n0 = xb * 16;

  __half (*ls)[1040] = (__half(*)[1040])smem;
  int a_loc = tid >> 4, i = tid & 15;
  int n = n0 + a_loc;
  {
    const float4* src = (const float4*)(x + (size_t)n*1024 + (size_t)i*64);
#pragma unroll
    for (int q = 0; q < 16; ++q){
      float4 v = src[q];
      int c = q*4;
      ls[a_loc][(c+0)*16 + i] = __float2half(v.x);
      ls[a_loc][(c+1)*16 + i] = __float2half(v.y);
      ls[a_loc][(c+2)*16 + i] = __float2half(v.z);
      ls[a_loc][(c+3)*16 + i] = __float2half(v.w);
    }
  }
  __syncthreads();

  int wid = tid >> 6, lane = tid & 63;
  for (int cp = 0; cp < 16; ++cp){
    int c = cp*4 + wid;
#pragma unroll
    for (int h = 0; h < 2; ++h){
      int a = h*8 + (lane >> 3), i2 = lane & 7;
      __half lo = ls[a][c*16 + 2*i2];
      __half hi = ls[a][c*16 + 2*i2 + 1];
      union { __half2 h2; unsigned u; } pk;
      pk.h2 = __halves2half2(lo, hi);
      xTu[((size_t)c*NATOMS + n0 + a)*8 + i2] = pk.u;
    }
  }
}

// ================= K2: main9 (standalone compile; proven v18 body) =================
__global__ __launch_bounds__(256, 4) void main9_kernel(
    const unsigned* __restrict__ xTu, const int* __restrict__ counts,
    const int* __restrict__ bins, const uint4* __restrict__ Bbuf,
    float* __restrict__ out){
  int v = (blockIdx.x & 7) * 96 + (blockIdx.x >> 3);   // bijective for 768
  int c = v / MAXBS;
  int g = v % MAXBS;
  int e, b0, cnt, ns;
  slot_decode(counts, g, e, b0, cnt, ns);
  if (g >= ns) return;

  int tid = threadIdx.x;
  int wid = tid >> 6, lane = tid & 63;

  __shared__ uint2 xe[256][19];
  __shared__ unsigned ltab[160];

  bool hi_half = (lane & 16) != 0;
  bool gsel    = (lane & 32) != 0;

  const uint4* xbase = (const uint4*)xTu;
  uint4 tv0[4], tv1[4];
  __half2 xsel[4][4];
#pragma unroll
  for (int T = 0; T < 4; ++T){
    int row = b0 + wid*64 + T*16 + (lane & 15);
    int n = (row < cnt) ? bins[e*NATOMS + row] : -1;
    if (n >= 0){
      const uint4* xr = xbase + ((size_t)c*NATOMS + n)*2;
      tv0[T] = xr[0];
      tv1[T] = xr[1];
    } else {
      tv0[T] = make_uint4(0,0,0,0);
      tv1[T] = make_uint4(0,0,0,0);
    }
    xsel[T][0] = uh(hi_half ? tv1[T].x : tv0[T].x);
    xsel[T][1] = uh(hi_half ? tv1[T].y : tv0[T].y);
    xsel[T][2] = uh(hi_half ? tv1[T].z : tv0[T].z);
    xsel[T][3] = uh(hi_half ? tv1[T].w : tv0[T].w);
  }
  {
    unsigned alo, ahi, blo, bhi;
    pack2(tv0[0].x, tv0[1].x, alo, ahi); pack2(tv0[2].x, tv0[3].x, blo, bhi);
    xe[tid][0] = make_uint2(alo, blo); xe[tid][1] = make_uint2(ahi, bhi);
    pack2(tv0[0].y, tv0[1].y, alo, ahi); pack2(tv0[2].y, tv0[3].y, blo, bhi);
    xe[tid][2] = make_uint2(alo, blo); xe[tid][3] = make_uint2(ahi, bhi);
    pack2(tv0[0].z, tv0[1].z, alo, ahi); pack2(tv0[2].z, tv0[3].z, blo, bhi);
    xe[tid][4] = make_uint2(alo, blo); xe[tid][5] = make_uint2(ahi, bhi);
    pack2(tv0[0].w, tv0[1].w, alo, ahi); pack2(tv0[2].w, tv0[3].w, blo, bhi);
    xe[tid][6] = make_uint2(alo, blo); xe[tid][7] = make_uint2(ahi, bhi);
    pack2(tv1[0].x, tv1[1].x, alo, ahi); pack2(tv1[2].x, tv1[3].x, blo, bhi);
    xe[tid][8] = make_uint2(alo, blo); xe[tid][9] = make_uint2(ahi, bhi);
    pack2(tv1[0].y, tv1[1].y, alo, ahi); pack2(tv1[2].y, tv1[3].y, blo, bhi);
    xe[tid][10] = make_uint2(alo, blo); xe[tid][11] = make_uint2(ahi, bhi);
    pack2(tv1[0].z, tv1[1].z, alo, ahi); pack2(tv1[2].z, tv1[3].z, blo, bhi);
    xe[tid][12] = make_uint2(alo, blo); xe[tid][13] = make_uint2(ahi, bhi);
    pack2(tv1[0].w, tv1[1].w, alo, ahi); pack2(tv1[2].w, tv1[3].w, blo, bhi);
    xe[tid][14] = make_uint2(alo, blo); xe[tid][15] = make_uint2(ahi, bhi);
    xe[tid][16] = make_uint2(0x3C003C00u, 0x3C003C00u);
    xe[tid][17] = make_uint2(0u, 0u);
  }
  if (tid < 160){
    unsigned ij;
    if (tid < NP)        ij = (unsigned)(pair_i(tid) | (pair_j(tid) << 8));
    else if (tid < 152)  ij = (unsigned)((tid - NP) | (16 << 8));
    else                 ij = (unsigned)(17 | (17 << 8));
    ltab[tid] = ij;
  }
  __syncthreads();

  const uint4* Bpan = Bbuf + (size_t)(e*CCH + c)*NSTEP*64 + lane;

  f32x4 acc0 = {0,0,0,0}, acc1 = {0,0,0,0}, acc2 = {0,0,0,0}, acc3 = {0,0,0,0};

  uint4 pb0 = Bpan[0*64], pb1 = Bpan[1*64], pb2 = Bpan[2*64], pb3 = Bpan[3*64];

  unsigned pk0 = ptab.v[0];
  int is = gsel ? ((pk0>>10)&31) : (pk0&31);
  int js = gsel ? ((pk0>>15)&31) : ((pk0>>5)&31);
  uint2 pi = xe[tid][is], pj = xe[tid][js];

#pragma unroll 4
  for (int s = 0; s < 68; ++s){
    uint2 npi = pi, npj = pj;
    if (s < 67){
      unsigned pk = ptab.v[s+1];
      int is2 = gsel ? ((pk>>10)&31) : (pk&31);
      int js2 = gsel ? ((pk>>15)&31) : ((pk>>5)&31);
      npi = xe[tid][is2]; npj = xe[tid][js2];
    }
    uint4 cur = pb0; pb0 = pb1; pb1 = pb2; pb2 = pb3;
    int ld = (s + 4 <= 72) ? (s + 4) : 72;
    pb3 = Bpan[(size_t)ld*64];

    __half2 p01 = __hmul2(uh(pi.x), uh(pj.x));
    __half2 p23 = __hmul2(uh(pi.y), uh(pj.y));

    union { uint4 u; f16x8 h; } bc; bc.u = cur;
    __half2 pv0 = __half2half2(__low2half(p01));
    __half2 pv1 = __half2half2(__high2half(p01));
    __half2 pv2 = __half2half2(__low2half(p23));
    __half2 pv3 = __half2half2(__high2half(p23));
    union { __half2 h[4]; f16x8 v; } u0, u1, u2, u3;
#pragma unroll
    for (int q = 0; q < 4; ++q){
      u0.h[q] = __hmul2(pv0, xsel[0][q]);
      u1.h[q] = __hmul2(pv1, xsel[1][q]);
      u2.h[q] = __hmul2(pv2, xsel[2][q]);
      u3.h[q] = __hmul2(pv3, xsel[3][q]);
    }
    acc0 = __builtin_amdgcn_mfma_f32_16x16x32_f16(u0.v, bc.h, acc0, 0,0,0);
    acc1 = __builtin_amdgcn_mfma_f32_16x16x32_f16(u1.v, bc.h, acc1, 0,0,0);
    acc2 = __builtin_amdgcn_mfma_f32_16x16x32_f16(u2.v, bc.h, acc2, 0,0,0);
    acc3 = __builtin_amdgcn_mfma_f32_16x16x32_f16(u3.v, bc.h, acc3, 0,0,0);
    pi = npi; pj = npj;
  }

  int g2 = (lane >> 4) & 3;
#pragma unroll
  for (int s = 68; s < 73; ++s){
    uint4 cur = pb0; pb0 = pb1; pb1 = pb2; pb2 = pb3;
    pb3 = Bpan[(size_t)72*64];
    int mb = 32*s + 8*g2 - M2B;
    union { uint4 u; f16x8 h; } bc; bc.u = cur;
    union { __half2 h[4]; f16x8 v; } u0, u1, u2, u3;
#pragma unroll
    for (int q = 0; q < 4; ++q){
      unsigned ta = ltab[mb + 2*q], tb = ltab[mb + 2*q + 1];
      uint2 A = xe[tid][ta & 255], B = xe[tid][ta >> 8];
      uint2 C = xe[tid][tb & 255], D = xe[tid][tb >> 8];
      __half2 pa01 = __hmul2(uh(A.x), uh(B.x));
      __half2 pb01 = __hmul2(uh(C.x), uh(D.x));
      __half2 pa23 = __hmul2(uh(A.y), uh(B.y));
      __half2 pb23 = __hmul2(uh(C.y), uh(D.y));
      u0.h[q] = __halves2half2(__low2half(pa01),  __low2half(pb01));
      u1.h[q] = __halves2half2(__high2half(pa01), __high2half(pb01));
      u2.h[q] = __halves2half2(__low2half(pa23),  __low2half(pb23));
      u3.h[q] = __halves2half2(__high2half(pa23), __high2half(pb23));
    }
    acc0 = __builtin_amdgcn_mfma_f32_16x16x32_f16(u0.v, bc.h, acc0, 0,0,0);
    acc1 = __builtin_amdgcn_mfma_f32_16x16x32_f16(u1.v, bc.h, acc1, 0,0,0);
    acc2 = __builtin_amdgcn_mfma_f32_16x16x32_f16(u2.v, bc.h, acc2, 0,0,0);
    acc3 = __builtin_amdgcn_mfma_f32_16x16x32_f16(u3.v, bc.h, acc3, 0,0,0);
  }

  int gp = lane >> 4, L = lane & 15;
#pragma unroll
  for (int T = 0; T < 4; ++T){
    f32x4 a = (T==0) ? acc0 : (T==1) ? acc1 : (T==2) ? acc2 : acc3;
    int rb = b0 + wid*64 + T*16;
#pragma unroll
    for (int r = 0; r < 4; ++r){
      int row = rb + 4*gp + r;
      if (row < cnt){
        int n = bins[e*NATOMS + row];
        out[((size_t)n*16 + L)*CCH + c] = a[r];
      }
    }
  }
}

extern "C" void kernel_launch(void* const* d_in, const int* in_sizes, int n_in,
                              void* d_out, int out_size, void* d_ws, size_t ws_size,
                              hipStream_t stream){
  const float* x   = (const float*)d_in[0];
  const int* types = (const int*)d_in[1];
  const float* U3  = (const float*)d_in[2];
  const float* U2  = (const float*)d_in[3];
  const float* U1  = (const float*)d_in[4];
  const float* W3  = (const float*)d_in[5];
  const float* W2  = (const float*)d_in[6];
  const float* W1  = (const float*)d_in[7];
  float* out = (float*)d_out;

  char* ws = (char*)d_ws;
  int* counts  = (int*)ws;               // written by prep_all block 0
  int* bins    = (int*)(ws + 1024);      // 32 KB

  const size_t bbOff   = 33792;
  const size_t bbBytes = (size_t)NE * 64 * NSTEP * 64 * 16;   // 19,136,512
  const size_t xtOff   = bbOff + bbBytes;                     // 19,170,304
  // xtBytes = 4,194,304 -> total ~23.4 MB

  unsigned int* Bbuf = (unsigned int*)(ws + bbOff);
  unsigned* xTu = (unsigned*)(ws + xtOff);

  prep_all<<<1 + 2*NSTEP*NE + 128, 256, 0, stream>>>(types, counts, bins,
                                                     U3, U2, U1, W3, W2, W1,
                                                     Bbuf, x, xTu);
  main9_kernel<<<GRIDN, 256, 0, stream>>>(xTu, counts, bins, (const uint4*)Bbuf, out);
}